// Round 2
// baseline (892.572 us; speedup 1.0000x reference)
//
#include <hip/hip_runtime.h>
#include <math.h>

#define Bn 4
#define Nn 512
#define Dn 64
#define Hn 8
#define ES 516  // ehat_s row stride in floats (8 rows -> 8 distinct banks)

typedef float f32x4 __attribute__((ext_vector_type(4)));

// ---------------- Kernel 1: QKV projection -------------------------------
__global__ __launch_bounds__(64) void qkv_kernel(
    const float* __restrict__ nin, const float* __restrict__ Wq,
    const float* __restrict__ Wk, const float* __restrict__ Wv,
    float* __restrict__ Qw, float* __restrict__ Kw, float* __restrict__ Vw)
{
    const int row = blockIdx.x;   // 0 .. B*N-1
    const int d = threadIdx.x;    // 0 .. 63
    __shared__ float nrow[Dn];
    nrow[d] = nin[row * Dn + d];
    __syncthreads();
    float aq = 0.f, ak = 0.f, av = 0.f;
#pragma unroll
    for (int k = 0; k < Dn; ++k) {
        const float nv = nrow[k];
        aq = fmaf(nv, Wq[k * Dn + d], aq);
        ak = fmaf(nv, Wk[k * Dn + d], ak);
        av = fmaf(nv, Wv[k * Dn + d], av);
    }
    Qw[row * Dn + d] = aq;
    Kw[row * Dn + d] = ak;
    Vw[row * Dn + d] = av;
}

// ---------------- Kernel 2: fused edge-bias attention ---------------------
// One block per (b,q). Phase 1: stream e rows (lane-owns-row, two half-row
// register chunks to stay <=128 VGPR), compute Eb/G/A/Ehat, write e_out
// (non-temporal) immediately, stash Ehat in LDS, accumulate sigmoid(G) sums.
// Phase 2: softmax over m (|Ehat| <= ~8, exp safe without max-subtract),
// P@V, dyn_centrality scaling, @Wo -> n_out.
__global__ __launch_bounds__(256, 4) void fused_kernel(
    const float* __restrict__ e,
    const float* __restrict__ Qw, const float* __restrict__ Kw,
    const float* __restrict__ Vw,
    const float* __restrict__ WeG, const float* __restrict__ WgG,
    const float* __restrict__ OeG, const float* __restrict__ WoG,
    float* __restrict__ nout, float* __restrict__ eout)
{
    const int bq = blockIdx.x;      // b*N + q
    const int b  = bq >> 9;         // N = 512
    const int t  = threadIdx.x;     // 0..255
    const int w  = t >> 6;          // wave 0..3
    const int l  = t & 63;          // lane 0..63

    __shared__ float ehat_s[Hn][ES];
    __shared__ __align__(16) float we_s[Hn][Dn];
    __shared__ __align__(16) float wg_s[Hn][Dn];
    __shared__ __align__(16) float oe_s[Hn][Dn];
    __shared__ __align__(16) float q_s[Dn];
    __shared__ float smb[4][Hn];
    __shared__ float gsb[4][Hn];
    __shared__ float accb[4][Dn];
    __shared__ float vo_s[Dn];

    // Stage weights. We/Wg are (D,H): transpose to [h][d]. Oe is (H,D): copy.
    for (int i = t; i < Dn * Hn; i += 256) {
        const int d = i >> 3, h = i & 7;
        we_s[h][d] = WeG[i];
        wg_s[h][d] = WgG[i];
        ((float*)oe_s)[i] = OeG[i];
    }
    if (t < Dn) q_s[t] = Qw[bq * Dn + t];
    __syncthreads();

    const float qscale = 0.35355339059327373f;  // 1/sqrt(8)
    float gpart[Hn];
#pragma unroll
    for (int h = 0; h < Hn; ++h) gpart[h] = 0.f;

    // ---------------- Phase 1: two rounds, m = rd*256 + t ----------------
    for (int rd = 0; rd < 2; ++rd) {
        const int m = rd * 256 + t;

        const float4* ep = (const float4*)(e + ((size_t)bq * Nn + m) * Dn);

        float eb[Hn], gg[Hn];
#pragma unroll
        for (int h = 0; h < Hn; ++h) { eb[h] = 0.f; gg[h] = 0.f; }

        // Two half-row passes: 8 x float4 in flight (32 VGPR), accumulate,
        // discard. Keeps total allocation under the 128-VGPR occupancy step.
#pragma unroll
        for (int half = 0; half < 2; ++half) {
            float4 ev[8];
#pragma unroll
            for (int j = 0; j < 8; ++j) ev[j] = ep[half * 8 + j];
#pragma unroll
            for (int d4 = 0; d4 < 8; ++d4) {
                const float4 e4 = ev[d4];
                const int wi = half * 8 + d4;
#pragma unroll
                for (int h = 0; h < Hn; ++h) {
                    const float4 w4 = ((const float4*)we_s[h])[wi];
                    const float4 g4 = ((const float4*)wg_s[h])[wi];
                    eb[h] = fmaf(e4.x, w4.x, fmaf(e4.y, w4.y,
                             fmaf(e4.z, w4.z, fmaf(e4.w, w4.w, eb[h]))));
                    gg[h] = fmaf(e4.x, g4.x, fmaf(e4.y, g4.y,
                             fmaf(e4.z, g4.z, fmaf(e4.w, g4.w, gg[h]))));
                }
            }
        }

        // A[h] = clip(Q.K * scale); Ehat = A + Eb; sigmoid(G) partial sums
        const float4* kp = (const float4*)(Kw + ((size_t)b * Nn + m) * Dn);
        const float4* q4 = (const float4*)q_s;
        float ehat[Hn];
#pragma unroll
        for (int h = 0; h < Hn; ++h) {
            const float4 k0 = kp[2 * h], k1 = kp[2 * h + 1];
            const float4 p0 = q4[2 * h], p1 = q4[2 * h + 1];
            float a = k0.x * p0.x + k0.y * p0.y + k0.z * p0.z + k0.w * p0.w
                    + k1.x * p1.x + k1.y * p1.y + k1.z * p1.z + k1.w * p1.w;
            a *= qscale;
            a = fminf(fmaxf(a, -5.f), 5.f);
            const float eh = a + eb[h];
            ehat[h] = eh;
            ehat_s[h][m] = eh;
            gpart[h] += 1.f / (1.f + __expf(-gg[h]));
        }

        // e_out row = Ehat(1x8) @ Oe(8x64); non-temporal (never re-read,
        // keep it from evicting e out of L3).
        float* eo = eout + ((size_t)bq * Nn + m) * Dn;
#pragma unroll
        for (int d4 = 0; d4 < 16; ++d4) {
            f32x4 o = {0.f, 0.f, 0.f, 0.f};
#pragma unroll
            for (int h = 0; h < Hn; ++h) {
                const float4 w4 = ((const float4*)oe_s[h])[d4];
                const float s = ehat[h];
                o.x = fmaf(s, w4.x, o.x);
                o.y = fmaf(s, w4.y, o.y);
                o.z = fmaf(s, w4.z, o.z);
                o.w = fmaf(s, w4.w, o.w);
            }
            __builtin_nontemporal_store(o, (f32x4*)eo + d4);
        }
    }
    __syncthreads();

    // ---------------- Phase 2: softmax + P@V ------------------------------
    const int h = l >> 3;
    float sm = 0.f, acc = 0.f;
    const float* vb = Vw + (size_t)b * Nn * Dn;
#pragma unroll 8
    for (int i = 0; i < 128; ++i) {
        const int m = w * 128 + i;
        const float p = __expf(ehat_s[h][m]);
        sm += p;
        acc = fmaf(p, vb[m * Dn + l], acc);
    }

    // reduce gpart across the wave (each lane covered distinct m's)
#pragma unroll
    for (int hh = 0; hh < Hn; ++hh) {
        float v = gpart[hh];
#pragma unroll
        for (int off = 32; off > 0; off >>= 1) v += __shfl_xor(v, off, 64);
        if (l == 0) gsb[w][hh] = v;
    }
    if ((l & 7) == 0) smb[w][h] = sm;
    accb[w][l] = acc;
    __syncthreads();

    if (w == 0) {
        float S = 0.f, O = 0.f, G = 0.f;
#pragma unroll
        for (int ww = 0; ww < 4; ++ww) {
            S += smb[ww][h];
            O += accb[ww][l];
            G += gsb[ww][h];
        }
        vo_s[l] = (O / S) * log1pf(G);
    }
    __syncthreads();

    if (w == 0) {
        float a2 = 0.f;
#pragma unroll
        for (int k = 0; k < Dn; ++k)
            a2 = fmaf(vo_s[k], WoG[k * Dn + l], a2);
        nout[(size_t)bq * Dn + l] = a2;
    }
}

// ---------------- Host launcher -------------------------------------------
extern "C" void kernel_launch(void* const* d_in, const int* in_sizes, int n_in,
                              void* d_out, int out_size, void* d_ws, size_t ws_size,
                              hipStream_t stream)
{
    (void)in_sizes; (void)n_in; (void)out_size; (void)ws_size;
    const float* nin = (const float*)d_in[0];
    const float* e   = (const float*)d_in[1];
    const float* Wq  = (const float*)d_in[2];
    const float* Wk  = (const float*)d_in[3];
    const float* Wv  = (const float*)d_in[4];
    const float* Wo  = (const float*)d_in[5];
    const float* Wg  = (const float*)d_in[6];
    const float* We  = (const float*)d_in[7];
    const float* Oe  = (const float*)d_in[8];

    float* Qw = (float*)d_ws;                 // B*N*D floats
    float* Kw = Qw + Bn * Nn * Dn;
    float* Vw = Kw + Bn * Nn * Dn;

    float* nout = (float*)d_out;              // B*N*D floats
    float* eout = nout + Bn * Nn * Dn;        // B*N*N*D floats

    qkv_kernel<<<Bn * Nn, 64, 0, stream>>>(nin, Wq, Wk, Wv, Qw, Kw, Vw);
    fused_kernel<<<Bn * Nn, 256, 0, stream>>>(e, Qw, Kw, Vw, We, Wg, Oe, Wo,
                                              nout, eout);
}

// Round 3
// 522.349 us; speedup vs baseline: 1.7088x; 1.7088x over previous
//
#include <hip/hip_runtime.h>
#include <math.h>

#define Bn 4
#define Nn 512
#define Dn 64
#define Hn 8
#define ES 516  // ehat_s row stride in floats (8 rows -> 8 distinct banks)

// ---------------- Kernel 1: QKV projection -------------------------------
__global__ __launch_bounds__(64) void qkv_kernel(
    const float* __restrict__ nin, const float* __restrict__ Wq,
    const float* __restrict__ Wk, const float* __restrict__ Wv,
    float* __restrict__ Qw, float* __restrict__ Kw, float* __restrict__ Vw)
{
    const int row = blockIdx.x;   // 0 .. B*N-1
    const int d = threadIdx.x;    // 0 .. 63
    __shared__ float nrow[Dn];
    nrow[d] = nin[row * Dn + d];
    __syncthreads();
    float aq = 0.f, ak = 0.f, av = 0.f;
#pragma unroll
    for (int k = 0; k < Dn; ++k) {
        const float nv = nrow[k];
        aq = fmaf(nv, Wq[k * Dn + d], aq);
        ak = fmaf(nv, Wk[k * Dn + d], ak);
        av = fmaf(nv, Wv[k * Dn + d], av);
    }
    Qw[row * Dn + d] = aq;
    Kw[row * Dn + d] = ak;
    Vw[row * Dn + d] = av;
}

// ---------------- Kernel 2: fused edge-bias attention ---------------------
// One block per (b,q). Phase 1: stream e rows (lane-owns-row, two half-row
// register chunks -> 64 VGPR, 42% occupancy), compute Eb/G/A/Ehat, write
// e_out (normal cached stores: L2 merges them into full lines), stash Ehat
// in LDS, accumulate sigmoid(G) sums. Phase 2: softmax over m (|Ehat|<=~8,
// exp safe without max-subtract), P@V, dyn_centrality scaling, @Wo -> n_out.
__global__ __launch_bounds__(256, 4) void fused_kernel(
    const float* __restrict__ e,
    const float* __restrict__ Qw, const float* __restrict__ Kw,
    const float* __restrict__ Vw,
    const float* __restrict__ WeG, const float* __restrict__ WgG,
    const float* __restrict__ OeG, const float* __restrict__ WoG,
    float* __restrict__ nout, float* __restrict__ eout)
{
    const int bq = blockIdx.x;      // b*N + q
    const int b  = bq >> 9;         // N = 512
    const int t  = threadIdx.x;     // 0..255
    const int w  = t >> 6;          // wave 0..3
    const int l  = t & 63;          // lane 0..63

    __shared__ float ehat_s[Hn][ES];
    __shared__ __align__(16) float we_s[Hn][Dn];
    __shared__ __align__(16) float wg_s[Hn][Dn];
    __shared__ __align__(16) float oe_s[Hn][Dn];
    __shared__ __align__(16) float q_s[Dn];
    __shared__ float smb[4][Hn];
    __shared__ float gsb[4][Hn];
    __shared__ float accb[4][Dn];
    __shared__ float vo_s[Dn];

    // Stage weights. We/Wg are (D,H): transpose to [h][d]. Oe is (H,D): copy.
    for (int i = t; i < Dn * Hn; i += 256) {
        const int d = i >> 3, h = i & 7;
        we_s[h][d] = WeG[i];
        wg_s[h][d] = WgG[i];
        ((float*)oe_s)[i] = OeG[i];
    }
    if (t < Dn) q_s[t] = Qw[bq * Dn + t];
    __syncthreads();

    const float qscale = 0.35355339059327373f;  // 1/sqrt(8)
    float gpart[Hn];
#pragma unroll
    for (int h = 0; h < Hn; ++h) gpart[h] = 0.f;

    // ---------------- Phase 1: two rounds, m = rd*256 + t ----------------
    for (int rd = 0; rd < 2; ++rd) {
        const int m = rd * 256 + t;

        const float4* ep = (const float4*)(e + ((size_t)bq * Nn + m) * Dn);

        float eb[Hn], gg[Hn];
#pragma unroll
        for (int h = 0; h < Hn; ++h) { eb[h] = 0.f; gg[h] = 0.f; }

        // Two half-row passes: 8 x float4 in flight (32 VGPR), accumulate,
        // discard. Keeps total allocation at the 64-VGPR occupancy step.
#pragma unroll
        for (int half = 0; half < 2; ++half) {
            float4 ev[8];
#pragma unroll
            for (int j = 0; j < 8; ++j) ev[j] = ep[half * 8 + j];
#pragma unroll
            for (int d4 = 0; d4 < 8; ++d4) {
                const float4 e4 = ev[d4];
                const int wi = half * 8 + d4;
#pragma unroll
                for (int h = 0; h < Hn; ++h) {
                    const float4 w4 = ((const float4*)we_s[h])[wi];
                    const float4 g4 = ((const float4*)wg_s[h])[wi];
                    eb[h] = fmaf(e4.x, w4.x, fmaf(e4.y, w4.y,
                             fmaf(e4.z, w4.z, fmaf(e4.w, w4.w, eb[h]))));
                    gg[h] = fmaf(e4.x, g4.x, fmaf(e4.y, g4.y,
                             fmaf(e4.z, g4.z, fmaf(e4.w, g4.w, gg[h]))));
                }
            }
        }

        // A[h] = clip(Q.K * scale); Ehat = A + Eb; sigmoid(G) partial sums
        const float4* kp = (const float4*)(Kw + ((size_t)b * Nn + m) * Dn);
        const float4* q4 = (const float4*)q_s;
        float ehat[Hn];
#pragma unroll
        for (int h = 0; h < Hn; ++h) {
            const float4 k0 = kp[2 * h], k1 = kp[2 * h + 1];
            const float4 p0 = q4[2 * h], p1 = q4[2 * h + 1];
            float a = k0.x * p0.x + k0.y * p0.y + k0.z * p0.z + k0.w * p0.w
                    + k1.x * p1.x + k1.y * p1.y + k1.z * p1.z + k1.w * p1.w;
            a *= qscale;
            a = fminf(fmaxf(a, -5.f), 5.f);
            const float eh = a + eb[h];
            ehat[h] = eh;
            ehat_s[h][m] = eh;
            gpart[h] += 1.f / (1.f + __expf(-gg[h]));
        }

        // e_out row = Ehat(1x8) @ Oe(8x64) — plain cached stores (L2 merges
        // 16B/lane into full lines; R2 showed nt stores cause 5x write amp).
        float* eo = eout + ((size_t)bq * Nn + m) * Dn;
#pragma unroll
        for (int d4 = 0; d4 < 16; ++d4) {
            float4 o; o.x = o.y = o.z = o.w = 0.f;
#pragma unroll
            for (int h = 0; h < Hn; ++h) {
                const float4 w4 = ((const float4*)oe_s[h])[d4];
                const float s = ehat[h];
                o.x = fmaf(s, w4.x, o.x);
                o.y = fmaf(s, w4.y, o.y);
                o.z = fmaf(s, w4.z, o.z);
                o.w = fmaf(s, w4.w, o.w);
            }
            ((float4*)eo)[d4] = o;
        }
    }
    __syncthreads();

    // ---------------- Phase 2: softmax + P@V ------------------------------
    const int h = l >> 3;
    float sm = 0.f, acc = 0.f;
    const float* vb = Vw + (size_t)b * Nn * Dn;
#pragma unroll 8
    for (int i = 0; i < 128; ++i) {
        const int m = w * 128 + i;
        const float p = __expf(ehat_s[h][m]);
        sm += p;
        acc = fmaf(p, vb[m * Dn + l], acc);
    }

    // reduce gpart across the wave (each lane covered distinct m's)
#pragma unroll
    for (int hh = 0; hh < Hn; ++hh) {
        float v = gpart[hh];
#pragma unroll
        for (int off = 32; off > 0; off >>= 1) v += __shfl_xor(v, off, 64);
        if (l == 0) gsb[w][hh] = v;
    }
    if ((l & 7) == 0) smb[w][h] = sm;
    accb[w][l] = acc;
    __syncthreads();

    if (w == 0) {
        float S = 0.f, O = 0.f, G = 0.f;
#pragma unroll
        for (int ww = 0; ww < 4; ++ww) {
            S += smb[ww][h];
            O += accb[ww][l];
            G += gsb[ww][h];
        }
        vo_s[l] = (O / S) * log1pf(G);
    }
    __syncthreads();

    if (w == 0) {
        float a2 = 0.f;
#pragma unroll
        for (int k = 0; k < Dn; ++k)
            a2 = fmaf(vo_s[k], WoG[k * Dn + l], a2);
        nout[(size_t)bq * Dn + l] = a2;
    }
}

// ---------------- Host launcher -------------------------------------------
extern "C" void kernel_launch(void* const* d_in, const int* in_sizes, int n_in,
                              void* d_out, int out_size, void* d_ws, size_t ws_size,
                              hipStream_t stream)
{
    (void)in_sizes; (void)n_in; (void)out_size; (void)ws_size;
    const float* nin = (const float*)d_in[0];
    const float* e   = (const float*)d_in[1];
    const float* Wq  = (const float*)d_in[2];
    const float* Wk  = (const float*)d_in[3];
    const float* Wv  = (const float*)d_in[4];
    const float* Wo  = (const float*)d_in[5];
    const float* Wg  = (const float*)d_in[6];
    const float* We  = (const float*)d_in[7];
    const float* Oe  = (const float*)d_in[8];

    float* Qw = (float*)d_ws;                 // B*N*D floats
    float* Kw = Qw + Bn * Nn * Dn;
    float* Vw = Kw + Bn * Nn * Dn;

    float* nout = (float*)d_out;              // B*N*D floats
    float* eout = nout + Bn * Nn * Dn;        // B*N*N*D floats

    qkv_kernel<<<Bn * Nn, 64, 0, stream>>>(nin, Wq, Wk, Wv, Qw, Kw, Vw);
    fused_kernel<<<Bn * Nn, 256, 0, stream>>>(e, Qw, Kw, Vw, We, Wg, Oe, Wo,
                                              nout, eout);
}

// Round 4
// 195.128 us; speedup vs baseline: 4.5743x; 2.6770x over previous
//
#include <hip/hip_runtime.h>
#include <hip/hip_fp16.h>
#include <math.h>

#define Bn 4
#define Nn 512
#define Dn 64
#define Hn 8
#define TR 64          // tile rows per block iteration
#define EW 68          // e_tile row stride in words; 68%32==4 -> rows shift banks
#define EHW 520        // ehat_s row stride in halfs

// ---------------- Kernel 1: QKV projection -------------------------------
__global__ __launch_bounds__(64) void qkv_kernel(
    const float* __restrict__ nin, const float* __restrict__ Wq,
    const float* __restrict__ Wk, const float* __restrict__ Wv,
    float* __restrict__ Qw, float* __restrict__ Kw, float* __restrict__ Vw)
{
    const int row = blockIdx.x;   // 0 .. B*N-1
    const int d = threadIdx.x;    // 0 .. 63
    __shared__ float nrow[Dn];
    nrow[d] = nin[row * Dn + d];
    __syncthreads();
    float aq = 0.f, ak = 0.f, av = 0.f;
#pragma unroll
    for (int k = 0; k < Dn; ++k) {
        const float nv = nrow[k];
        aq = fmaf(nv, Wq[k * Dn + d], aq);
        ak = fmaf(nv, Wk[k * Dn + d], ak);
        av = fmaf(nv, Wv[k * Dn + d], av);
    }
    Qw[row * Dn + d] = aq;
    Kw[row * Dn + d] = ak;
    Vw[row * Dn + d] = av;
}

// ---------------- Kernel 2: fused edge-bias attention ---------------------
// One block per (b,q). 8 tiles of 64 m-rows. Per tile:
//   stage: coalesced 1KB/wave global loads -> regs -> padded LDS tile
//   compute: wave w owns heads {2w,2w+1}, lane = row; eb/gg/A/ehat; ehat->LDS f16
//   e_out: all-h pass reads ehat, writes out-tile into (dead) e-tile
//   flush: linear coalesced 1KB/wave stores (full cache lines -> no write amp)
// Phase 2: softmax over m (|ehat|<=~8, exp safe), P@V, centrality, @Wo.
__global__ __launch_bounds__(256, 4) void fused_kernel(
    const float* __restrict__ e,
    const float* __restrict__ Qw, const float* __restrict__ Kw,
    const float* __restrict__ Vw,
    const float* __restrict__ WeG, const float* __restrict__ WgG,
    const float* __restrict__ OeG, const float* __restrict__ WoG,
    float* __restrict__ nout, float* __restrict__ eout)
{
    const int bq = blockIdx.x;      // b*N + q
    const int b  = bq >> 9;         // N = 512
    const int t  = threadIdx.x;     // 0..255
    const int w  = t >> 6;          // wave 0..3 = head-pair {2w,2w+1}
    const int l  = t & 63;          // lane 0..63 = row within tile

    __shared__ float  e_tile[TR * EW];             // 17408 B, padded
    __shared__ __half ehat_s[Hn * EHW];            // 8320 B
    __shared__ __align__(16) float we_s[Hn][Dn];   // [h][d]
    __shared__ __align__(16) float wg_s[Hn][Dn];
    __shared__ __align__(16) float oe_s[Hn][Dn];
    __shared__ float gsum_s[Hn];
    __shared__ float smb[4][Hn];
    __shared__ float accb[4][Dn];
    __shared__ float vo_s[Dn];

    // Stage weights. We/Wg are (D,H): transpose to [h][d]. Oe is (H,D): copy.
    for (int i = t; i < Dn * Hn; i += 256) {
        const int d = i >> 3, h = i & 7;
        we_s[h][d] = WeG[i];
        wg_s[h][d] = WgG[i];
        ((float*)oe_s)[i] = OeG[i];
    }

    // Q cols for this wave's head-pair: 16 floats, wave-uniform (L1 broadcast)
    float4 q0, q1, q2, q3;
    {
        const float4* qp = (const float4*)(Qw + (size_t)bq * Dn + w * 16);
        q0 = qp[0]; q1 = qp[1]; q2 = qp[2]; q3 = qp[3];
    }
    __syncthreads();   // weights visible

    const float qscale = 0.35355339059327373f;  // 1/sqrt(8)
    float gpart0 = 0.f, gpart1 = 0.f;

    // Prologue: stage tile 0 into regs (coalesced: chunk c = j*256+t, 1KB/wave)
    float4 st[4];
    {
        const float4* ep = (const float4*)(e + (size_t)bq * Nn * Dn);
#pragma unroll
        for (int j = 0; j < 4; ++j) st[j] = ep[j * 256 + t];
    }

    for (int tile = 0; tile < Nn / TR; ++tile) {
        const int m0 = tile * TR;
        const int m  = m0 + l;

        __syncthreads();   // (a) previous flush done reading e_tile
        // regs -> padded LDS tile
#pragma unroll
        for (int j = 0; j < 4; ++j) {
            const int c = j * 256 + t;          // chunk 0..1023
            const int r = c >> 4, cc = c & 15;
            *(float4*)&e_tile[r * EW + cc * 4] = st[j];
        }
        __syncthreads();   // (b) tile visible to all waves

        // prefetch next tile into regs (in flight across compute)
        if (tile + 1 < Nn / TR) {
            const float4* ep = (const float4*)(e + ((size_t)bq * Nn + m0 + TR) * Dn);
#pragma unroll
            for (int j = 0; j < 4; ++j) st[j] = ep[j * 256 + t];
        }

        // ---- compute: lane = row m, heads {2w, 2w+1} ----
        float eb0 = 0.f, eb1 = 0.f, gg0 = 0.f, gg1 = 0.f;
        const float4* we0 = (const float4*)we_s[2 * w];
        const float4* we1 = (const float4*)we_s[2 * w + 1];
        const float4* wg0 = (const float4*)wg_s[2 * w];
        const float4* wg1 = (const float4*)wg_s[2 * w + 1];
#pragma unroll
        for (int d4 = 0; d4 < 16; ++d4) {
            const float4 e4 = *(const float4*)&e_tile[l * EW + d4 * 4];
            const float4 a0 = we0[d4], a1 = we1[d4];
            const float4 g0 = wg0[d4], g1 = wg1[d4];
            eb0 = fmaf(e4.x, a0.x, fmaf(e4.y, a0.y, fmaf(e4.z, a0.z, fmaf(e4.w, a0.w, eb0))));
            eb1 = fmaf(e4.x, a1.x, fmaf(e4.y, a1.y, fmaf(e4.z, a1.z, fmaf(e4.w, a1.w, eb1))));
            gg0 = fmaf(e4.x, g0.x, fmaf(e4.y, g0.y, fmaf(e4.z, g0.z, fmaf(e4.w, g0.w, gg0))));
            gg1 = fmaf(e4.x, g1.x, fmaf(e4.y, g1.y, fmaf(e4.z, g1.z, fmaf(e4.w, g1.w, gg1))));
        }

        // A for the 2 heads: K[b][m][16w..16w+15] (64B/lane, full lines, L2-hot)
        {
            const float4* kp = (const float4*)(Kw + ((size_t)b * Nn + m) * Dn + w * 16);
            const float4 k0 = kp[0], k1 = kp[1], k2 = kp[2], k3 = kp[3];
            float a0 = k0.x*q0.x + k0.y*q0.y + k0.z*q0.z + k0.w*q0.w
                     + k1.x*q1.x + k1.y*q1.y + k1.z*q1.z + k1.w*q1.w;
            float a1 = k2.x*q2.x + k2.y*q2.y + k2.z*q2.z + k2.w*q2.w
                     + k3.x*q3.x + k3.y*q3.y + k3.z*q3.z + k3.w*q3.w;
            a0 = fminf(fmaxf(a0 * qscale, -5.f), 5.f);
            a1 = fminf(fmaxf(a1 * qscale, -5.f), 5.f);
            ehat_s[(2 * w) * EHW + m]     = __float2half(a0 + eb0);
            ehat_s[(2 * w + 1) * EHW + m] = __float2half(a1 + eb1);
        }
        gpart0 += 1.f / (1.f + __expf(-gg0));
        gpart1 += 1.f / (1.f + __expf(-gg1));

        __syncthreads();   // (c) ehat complete; everyone done reading e_tile

        // ---- e_out pass: thread t -> row l, col segment w*16..w*16+15 ----
        {
            float eh[Hn];
#pragma unroll
            for (int h = 0; h < Hn; ++h)
                eh[h] = __half2float(ehat_s[h * EHW + m]);
#pragma unroll
            for (int j = 0; j < 4; ++j) {
                float4 o; o.x = o.y = o.z = o.w = 0.f;
#pragma unroll
                for (int h = 0; h < Hn; ++h) {
                    const float4 w4 = *(const float4*)&oe_s[h][w * 16 + j * 4];
                    o.x = fmaf(eh[h], w4.x, o.x);
                    o.y = fmaf(eh[h], w4.y, o.y);
                    o.z = fmaf(eh[h], w4.z, o.z);
                    o.w = fmaf(eh[h], w4.w, o.w);
                }
                *(float4*)&e_tile[l * EW + w * 16 + j * 4] = o;
            }
        }
        __syncthreads();   // (d) out-tile complete

        // ---- flush: linear coalesced stores, 1KB per wave instruction ----
        {
            float4* eo = (float4*)(eout + ((size_t)bq * Nn + m0) * Dn);
#pragma unroll
            for (int j = 0; j < 4; ++j) {
                const int c = j * 256 + t;
                const int r = c >> 4, cc = c & 15;
                eo[c] = *(const float4*)&e_tile[r * EW + cc * 4];
            }
        }
    }

    // dyn centrality: reduce gpart over 64 lanes (rows), per head-pair
    {
        float v0 = gpart0, v1 = gpart1;
#pragma unroll
        for (int off = 32; off > 0; off >>= 1) {
            v0 += __shfl_xor(v0, off, 64);
            v1 += __shfl_xor(v1, off, 64);
        }
        if (l == 0) { gsum_s[2 * w] = v0; gsum_s[2 * w + 1] = v1; }
    }
    __syncthreads();

    // ---------------- Phase 2: softmax + P@V ------------------------------
    const int h2 = l >> 3;      // lane l: output col l = h2*8 + dk
    float sm = 0.f, acc = 0.f;
    const float* vb = Vw + (size_t)b * Nn * Dn;
#pragma unroll 8
    for (int i = 0; i < 128; ++i) {
        const int mm = w * 128 + i;
        const float p = __expf(__half2float(ehat_s[h2 * EHW + mm]));
        sm += p;
        acc = fmaf(p, vb[mm * Dn + l], acc);
    }
    if ((l & 7) == 0) smb[w][h2] = sm;
    accb[w][l] = acc;
    __syncthreads();

    if (w == 0) {
        float S = 0.f, O = 0.f;
#pragma unroll
        for (int ww = 0; ww < 4; ++ww) { S += smb[ww][h2]; O += accb[ww][l]; }
        vo_s[l] = (O / S) * log1pf(gsum_s[h2]);
    }
    __syncthreads();

    if (w == 0) {
        float a2 = 0.f;
#pragma unroll
        for (int k = 0; k < Dn; ++k)
            a2 = fmaf(vo_s[k], WoG[k * Dn + l], a2);
        nout[(size_t)bq * Dn + l] = a2;
    }
}

// ---------------- Host launcher -------------------------------------------
extern "C" void kernel_launch(void* const* d_in, const int* in_sizes, int n_in,
                              void* d_out, int out_size, void* d_ws, size_t ws_size,
                              hipStream_t stream)
{
    (void)in_sizes; (void)n_in; (void)out_size; (void)ws_size;
    const float* nin = (const float*)d_in[0];
    const float* e   = (const float*)d_in[1];
    const float* Wq  = (const float*)d_in[2];
    const float* Wk  = (const float*)d_in[3];
    const float* Wv  = (const float*)d_in[4];
    const float* Wo  = (const float*)d_in[5];
    const float* Wg  = (const float*)d_in[6];
    const float* We  = (const float*)d_in[7];
    const float* Oe  = (const float*)d_in[8];

    float* Qw = (float*)d_ws;                 // B*N*D floats
    float* Kw = Qw + Bn * Nn * Dn;
    float* Vw = Kw + Bn * Nn * Dn;

    float* nout = (float*)d_out;              // B*N*D floats
    float* eout = nout + Bn * Nn * Dn;        // B*N*N*D floats

    qkv_kernel<<<Bn * Nn, 64, 0, stream>>>(nin, Wq, Wk, Wv, Qw, Kw, Vw);
    fused_kernel<<<Bn * Nn, 256, 0, stream>>>(e, Qw, Kw, Vw, We, Wg, Oe, Wo,
                                              nout, eout);
}

// Round 5
// 138.786 us; speedup vs baseline: 6.4313x; 1.4060x over previous
//
#include <hip/hip_runtime.h>
#include <math.h>

#define Bn 4
#define Nn 512
#define Dn 64
#define Hn 8
#define TR 64          // rows per tile-block
#define NT (Nn / TR)   // 8 tiles per (b,q)
#define EW 68          // e_tile row stride (words); 68%32==4 spreads banks
#define PS 68          // ehat/p row stride (words); 8 heads -> 8 distinct banks
#define PART 80        // partial floats per block: 64 PV + 8 expsum + 8 gsum

// ---------------- Kernel 1: QKV projection -------------------------------
__global__ __launch_bounds__(64) void qkv_kernel(
    const float* __restrict__ nin, const float* __restrict__ Wq,
    const float* __restrict__ Wk, const float* __restrict__ Wv,
    float* __restrict__ Qw, float* __restrict__ Kw, float* __restrict__ Vw)
{
    const int row = blockIdx.x;   // 0 .. B*N-1
    const int d = threadIdx.x;    // 0 .. 63
    __shared__ float nrow[Dn];
    nrow[d] = nin[row * Dn + d];
    __syncthreads();
    float aq = 0.f, ak = 0.f, av = 0.f;
#pragma unroll
    for (int k = 0; k < Dn; ++k) {
        const float nv = nrow[k];
        aq = fmaf(nv, Wq[k * Dn + d], aq);
        ak = fmaf(nv, Wk[k * Dn + d], ak);
        av = fmaf(nv, Wv[k * Dn + d], av);
    }
    Qw[row * Dn + d] = aq;
    Kw[row * Dn + d] = ak;
    Vw[row * Dn + d] = av;
}

// ---------------- Kernel 2: streaming tile kernel -------------------------
// One block per (b,q,tile): 64 m-rows. Coalesced 16KB e-read -> LDS ->
// eb/gg/A/ehat (wave = head-pair, lane = row) -> e_out via LDS transpose ->
// coalesced 16KB flush -> 80-float partial (PV, expsum, gsum) to workspace.
// No cross-tile state, no atomics; reduce_kernel folds partials into n_out.
__global__ __launch_bounds__(256, 5) void stream_kernel(
    const float* __restrict__ e,
    const float* __restrict__ Qw, const float* __restrict__ Kw,
    const float* __restrict__ Vw,
    const float* __restrict__ WeG, const float* __restrict__ WgG,
    const float* __restrict__ OeG,
    float* __restrict__ eout, float* __restrict__ part)
{
    const int bid  = blockIdx.x;        // bq*NT + tile
    const int bq   = bid >> 3;          // NT = 8
    const int tile = bid & 7;
    const int b    = bq >> 9;           // N = 512
    const int m0   = tile * TR;
    const int t    = threadIdx.x;       // 0..255
    const int w    = t >> 6;            // wave 0..3 = head-pair {2w,2w+1}
    const int l    = t & 63;            // lane 0..63 = row within tile

    __shared__ float e_tile[TR * EW];               // 17408 B
    __shared__ float ehat_s[Hn * PS];               // 2176 B
    __shared__ float p_s[Hn * PS];                  // 2176 B
    __shared__ __align__(16) float we_s[Hn][Dn];    // [h][d]
    __shared__ __align__(16) float wg_s[Hn][Dn];
    __shared__ __align__(16) float oe_s[Hn][Dn];
    __shared__ float accb[4][Dn];
    __shared__ float psb[4][Dn];
    __shared__ float gsb[4][Hn];

    // 1) e-tile loads first (HBM, longest latency): 16KB contiguous
    float4 st[4];
    {
        const float4* ep = (const float4*)(e + ((size_t)bq * Nn + m0) * Dn);
#pragma unroll
        for (int j = 0; j < 4; ++j) st[j] = ep[j * 256 + t];
    }

    // 2) K slice for this wave's head-pair (L2-hot: shared across 512 q's)
    float a0, a1;
    {
        const float4* kp = (const float4*)(Kw + ((size_t)b * Nn + m0 + l) * Dn + w * 16);
        const float4 k0 = kp[0], k1 = kp[1], k2 = kp[2], k3 = kp[3];
        const float4* qp = (const float4*)(Qw + (size_t)bq * Dn + w * 16);
        const float4 q0 = qp[0], q1 = qp[1], q2 = qp[2], q3 = qp[3];
        const float qscale = 0.35355339059327373f;  // 1/sqrt(8)
        a0 = k0.x*q0.x + k0.y*q0.y + k0.z*q0.z + k0.w*q0.w
           + k1.x*q1.x + k1.y*q1.y + k1.z*q1.z + k1.w*q1.w;
        a1 = k2.x*q2.x + k2.y*q2.y + k2.z*q2.z + k2.w*q2.w
           + k3.x*q3.x + k3.y*q3.y + k3.z*q3.z + k3.w*q3.w;
        a0 = fminf(fmaxf(a0 * qscale, -5.f), 5.f);
        a1 = fminf(fmaxf(a1 * qscale, -5.f), 5.f);
    }

    // 3) weights (L2-hot broadcast). We/Wg (D,H) -> [h][d]; Oe (H,D) copy.
    for (int i = t; i < Dn * Hn; i += 256) {
        const int d = i >> 3, h = i & 7;
        we_s[h][d] = WeG[i];
        wg_s[h][d] = WgG[i];
        ((float*)oe_s)[i] = OeG[i];
    }

    // 4) staged e -> padded LDS tile (waits on vmcnt for st)
#pragma unroll
    for (int j = 0; j < 4; ++j) {
        const int c = j * 256 + t, r = c >> 4, cc = c & 15;
        *(float4*)&e_tile[r * EW + cc * 4] = st[j];
    }
    __syncthreads();

    // 5) eb/gg dots: lane = row, weights broadcast from LDS
    float eb0 = 0.f, eb1 = 0.f, gg0 = 0.f, gg1 = 0.f;
    {
        const float4* we0 = (const float4*)we_s[2 * w];
        const float4* we1 = (const float4*)we_s[2 * w + 1];
        const float4* wg0 = (const float4*)wg_s[2 * w];
        const float4* wg1 = (const float4*)wg_s[2 * w + 1];
#pragma unroll
        for (int d4 = 0; d4 < 16; ++d4) {
            const float4 e4 = *(const float4*)&e_tile[l * EW + d4 * 4];
            const float4 A0 = we0[d4], A1 = we1[d4];
            const float4 G0 = wg0[d4], G1 = wg1[d4];
            eb0 = fmaf(e4.x, A0.x, fmaf(e4.y, A0.y, fmaf(e4.z, A0.z, fmaf(e4.w, A0.w, eb0))));
            eb1 = fmaf(e4.x, A1.x, fmaf(e4.y, A1.y, fmaf(e4.z, A1.z, fmaf(e4.w, A1.w, eb1))));
            gg0 = fmaf(e4.x, G0.x, fmaf(e4.y, G0.y, fmaf(e4.z, G0.z, fmaf(e4.w, G0.w, gg0))));
            gg1 = fmaf(e4.x, G1.x, fmaf(e4.y, G1.y, fmaf(e4.z, G1.z, fmaf(e4.w, G1.w, gg1))));
        }
    }

    // 6) ehat, p = exp(ehat) (|ehat| <= ~8: exp safe in f32), gate partials
    {
        const float eh0 = a0 + eb0, eh1 = a1 + eb1;
        ehat_s[(2 * w) * PS + l]     = eh0;
        ehat_s[(2 * w + 1) * PS + l] = eh1;
        p_s[(2 * w) * PS + l]     = __expf(eh0);
        p_s[(2 * w + 1) * PS + l] = __expf(eh1);
        float g0 = 1.f / (1.f + __expf(-gg0));
        float g1 = 1.f / (1.f + __expf(-gg1));
#pragma unroll
        for (int off = 32; off > 0; off >>= 1) {
            g0 += __shfl_xor(g0, off, 64);
            g1 += __shfl_xor(g1, off, 64);
        }
        if (l == 0) { gsb[w][2 * w] = g0; gsb[w][2 * w + 1] = g1; }
    }
    __syncthreads();   // ehat/p ready; eb-phase done reading e_tile

    // 7) e_out pass: thread (w,l) -> row l, col segment w*16..w*16+15
    {
        float eh[Hn];
#pragma unroll
        for (int h = 0; h < Hn; ++h) eh[h] = ehat_s[h * PS + l];
#pragma unroll
        for (int j = 0; j < 4; ++j) {
            float4 o; o.x = o.y = o.z = o.w = 0.f;
#pragma unroll
            for (int h = 0; h < Hn; ++h) {
                const float4 w4 = *(const float4*)&oe_s[h][w * 16 + j * 4];
                o.x = fmaf(eh[h], w4.x, o.x);
                o.y = fmaf(eh[h], w4.y, o.y);
                o.z = fmaf(eh[h], w4.z, o.z);
                o.w = fmaf(eh[h], w4.w, o.w);
            }
            *(float4*)&e_tile[l * EW + w * 16 + j * 4] = o;
        }
    }
    __syncthreads();   // out-tile complete

    // 8) flush: coalesced full-line stores, 16KB contiguous per block
    {
        float4* eo = (float4*)(eout + ((size_t)bq * Nn + m0) * Dn);
#pragma unroll
        for (int j = 0; j < 4; ++j) {
            const int c = j * 256 + t;
            eo[c] = *(const float4*)&e_tile[(c >> 4) * EW + (c & 15) * 4];
        }
    }

    // 9) PV + expsum partials: wave w covers i in [w*16, w*16+16)
    {
        const int h = l >> 3;
        float acc = 0.f, ps = 0.f;
        const float* vrow = Vw + ((size_t)b * Nn + m0 + w * 16) * Dn;
#pragma unroll
        for (int i = 0; i < 16; ++i) {
            const float p = p_s[h * PS + w * 16 + i];
            ps += p;
            acc = fmaf(p, vrow[i * Dn + l], acc);
        }
        accb[w][l] = acc;
        psb[w][l]  = ps;
    }
    __syncthreads();

    // 10) fold 4 waves, emit 80-float partial
    if (w == 0) {
        const int h = l >> 3;
        const float O = accb[0][l] + accb[1][l] + accb[2][l] + accb[3][l];
        const float S = psb[0][l] + psb[1][l] + psb[2][l] + psb[3][l];
        float* pb = part + (size_t)bid * PART;
        pb[l] = O;
        if ((l & 7) == 0) pb[64 + h] = S;
        if (l < 8)        pb[72 + l] = gsb[l >> 1][l];
    }
}

// ---------------- Kernel 3: fold partials -> n_out ------------------------
__global__ __launch_bounds__(64) void reduce_kernel(
    const float* __restrict__ part, const float* __restrict__ WoG,
    float* __restrict__ nout)
{
    const int bq = blockIdx.x;
    const int l  = threadIdx.x;
    const int h  = l >> 3;
    const float* pb = part + (size_t)bq * NT * PART;
    float O = 0.f, S = 0.f, G = 0.f;
#pragma unroll
    for (int tl = 0; tl < NT; ++tl) {
        O += pb[tl * PART + l];
        S += pb[tl * PART + 64 + h];
        G += pb[tl * PART + 72 + h];
    }
    __shared__ float vo_s[Dn];
    vo_s[l] = (O / S) * log1pf(G);
    __syncthreads();
    float a = 0.f;
#pragma unroll
    for (int k = 0; k < Dn; ++k)
        a = fmaf(vo_s[k], WoG[k * Dn + l], a);
    nout[(size_t)bq * Dn + l] = a;
}

// ---------------- Host launcher -------------------------------------------
extern "C" void kernel_launch(void* const* d_in, const int* in_sizes, int n_in,
                              void* d_out, int out_size, void* d_ws, size_t ws_size,
                              hipStream_t stream)
{
    (void)in_sizes; (void)n_in; (void)out_size; (void)ws_size;
    const float* nin = (const float*)d_in[0];
    const float* e   = (const float*)d_in[1];
    const float* Wq  = (const float*)d_in[2];
    const float* Wk  = (const float*)d_in[3];
    const float* Wv  = (const float*)d_in[4];
    const float* Wo  = (const float*)d_in[5];
    const float* Wg  = (const float*)d_in[6];
    const float* We  = (const float*)d_in[7];
    const float* Oe  = (const float*)d_in[8];

    float* Qw   = (float*)d_ws;               // B*N*D floats
    float* Kw   = Qw + Bn * Nn * Dn;
    float* Vw   = Kw + Bn * Nn * Dn;
    float* part = Vw + Bn * Nn * Dn;          // B*N*NT*PART floats (5.2 MB)

    float* nout = (float*)d_out;              // B*N*D floats
    float* eout = nout + Bn * Nn * Dn;        // B*N*N*D floats

    qkv_kernel<<<Bn * Nn, 64, 0, stream>>>(nin, Wq, Wk, Wv, Qw, Kw, Vw);
    stream_kernel<<<Bn * Nn * NT, 256, 0, stream>>>(e, Qw, Kw, Vw, We, Wg, Oe,
                                                    eout, part);
    reduce_kernel<<<Bn * Nn, 64, 0, stream>>>(part, Wo, nout);
}

// Round 6
// 130.488 us; speedup vs baseline: 6.8403x; 1.0636x over previous
//
#include <hip/hip_runtime.h>
#include <math.h>

#define Bn 4
#define Nn 512
#define Dn 64
#define Hn 8
#define TR 64          // rows per tile-block
#define NT (Nn / TR)   // 8 tiles per (b,q)
#define PS 68          // ehat row stride (words); 8 heads -> 8 distinct banks
#define PART 80        // partial floats per block: 64 PV + 8 expsum + 8 gsum

typedef float f32x4 __attribute__((ext_vector_type(4)));

// ---------------- Kernel 1: QKV projection -------------------------------
__global__ __launch_bounds__(64) void qkv_kernel(
    const float* __restrict__ nin, const float* __restrict__ Wq,
    const float* __restrict__ Wk, const float* __restrict__ Wv,
    float* __restrict__ Qw, float* __restrict__ Kw, float* __restrict__ Vw)
{
    const int row = blockIdx.x;   // 0 .. B*N-1
    const int d = threadIdx.x;    // 0 .. 63
    __shared__ float nrow[Dn];
    nrow[d] = nin[row * Dn + d];
    __syncthreads();
    float aq = 0.f, ak = 0.f, av = 0.f;
#pragma unroll
    for (int k = 0; k < Dn; ++k) {
        const float nv = nrow[k];
        aq = fmaf(nv, Wq[k * Dn + d], aq);
        ak = fmaf(nv, Wk[k * Dn + d], ak);
        av = fmaf(nv, Wv[k * Dn + d], av);
    }
    Qw[row * Dn + d] = aq;
    Kw[row * Dn + d] = ak;
    Vw[row * Dn + d] = av;
}

// ---------------- Kernel 2: streaming tile kernel -------------------------
// One block per (b,q,tile): 64 m-rows. Coalesced 16KB e-read -> XOR-swizzled
// LDS tile (<=2-way bank aliasing on both write and read) -> eb/gg/A/ehat
// (wave = head-pair, lane = row) -> e_out computed per-output-chunk and
// nt-stored directly (full-line coalesced; bypasses L2/L3 so e stays
// L3-resident across replays) -> PV/expsum/gsum partial to workspace.
__global__ __launch_bounds__(256, 6) void stream_kernel(
    const float* __restrict__ e,
    const float* __restrict__ Qw, const float* __restrict__ Kw,
    const float* __restrict__ Vw,
    const float* __restrict__ WeG, const float* __restrict__ WgG,
    const float* __restrict__ OeG,
    float* __restrict__ eout, float* __restrict__ part)
{
    const int bid  = blockIdx.x;        // bq*NT + tile
    const int bq   = bid >> 3;          // NT = 8
    const int tile = bid & 7;
    const int b    = bq >> 9;           // N = 512
    const int m0   = tile * TR;
    const int t    = threadIdx.x;       // 0..255
    const int w    = t >> 6;            // wave 0..3 = head-pair {2w,2w+1}
    const int l    = t & 63;            // lane 0..63 = row within tile

    __shared__ float e_tile[TR * Dn];               // 16384 B, swizzled groups
    __shared__ float ehat_s[Hn * PS];               // 2176 B
    __shared__ __align__(16) float we_s[Hn][Dn];    // [h][d]  2048 B
    __shared__ __align__(16) float wg_s[Hn][Dn];    // 2048 B
    __shared__ __align__(16) float oe_s[Hn][Dn];    // 2048 B
    __shared__ float accb[4][Dn];                   // 1024 B
    __shared__ float ssb[Hn], gsb[Hn];              // 64 B

    // 1) e-tile loads first (HBM latency): 16KB contiguous, 4 float4/thread
    float4 st[4];
    {
        const float4* ep = (const float4*)(e + ((size_t)bq * Nn + m0) * Dn);
#pragma unroll
        for (int j = 0; j < 4; ++j) st[j] = ep[j * 256 + t];
    }

    // 2) K slice for this wave's head-pair (L2-hot) + Q (wave-uniform)
    float a0, a1;
    {
        const float4* kp = (const float4*)(Kw + ((size_t)b * Nn + m0 + l) * Dn + w * 16);
        const float4 k0 = kp[0], k1 = kp[1], k2 = kp[2], k3 = kp[3];
        const float4* qp = (const float4*)(Qw + (size_t)bq * Dn + w * 16);
        const float4 q0 = qp[0], q1 = qp[1], q2 = qp[2], q3 = qp[3];
        const float qscale = 0.35355339059327373f;  // 1/sqrt(8)
        a0 = k0.x*q0.x + k0.y*q0.y + k0.z*q0.z + k0.w*q0.w
           + k1.x*q1.x + k1.y*q1.y + k1.z*q1.z + k1.w*q1.w;
        a1 = k2.x*q2.x + k2.y*q2.y + k2.z*q2.z + k2.w*q2.w
           + k3.x*q3.x + k3.y*q3.y + k3.z*q3.z + k3.w*q3.w;
        a0 = fminf(fmaxf(a0 * qscale, -5.f), 5.f);
        a1 = fminf(fmaxf(a1 * qscale, -5.f), 5.f);
    }

    // 3) weights (L2-hot). We/Wg (D,H) -> [h][d]; Oe (H,D) copy.
    for (int i = t; i < Dn * Hn; i += 256) {
        const int d = i >> 3, h = i & 7;
        we_s[h][d] = WeG[i];
        wg_s[h][d] = WgG[i];
        ((float*)oe_s)[i] = OeG[i];
    }

    // 4) staged e -> swizzled LDS: global chunk (r,g) -> slot (r, g^(r&15)).
    //    Write: 16 lanes/row contiguous-permuted 256B -> <=2-way banks.
#pragma unroll
    for (int j = 0; j < 4; ++j) {
        const int c = j * 256 + t, r = c >> 4, g = c & 15;
        *(float4*)&e_tile[r * Dn + ((g ^ (r & 15)) << 2)] = st[j];
    }
    __syncthreads();

    // 5) eb/gg dots: lane = row l, read slot (l, d4^(l&15)) = global (l, d4)
    float eb0 = 0.f, eb1 = 0.f, gg0 = 0.f, gg1 = 0.f;
    {
        const float4* we0 = (const float4*)we_s[2 * w];
        const float4* we1 = (const float4*)we_s[2 * w + 1];
        const float4* wg0 = (const float4*)wg_s[2 * w];
        const float4* wg1 = (const float4*)wg_s[2 * w + 1];
#pragma unroll
        for (int d4 = 0; d4 < 16; ++d4) {
            const float4 e4 = *(const float4*)&e_tile[l * Dn + (((d4 ^ (l & 15))) << 2)];
            const float4 A0 = we0[d4], A1 = we1[d4];
            const float4 G0 = wg0[d4], G1 = wg1[d4];
            eb0 = fmaf(e4.x, A0.x, fmaf(e4.y, A0.y, fmaf(e4.z, A0.z, fmaf(e4.w, A0.w, eb0))));
            eb1 = fmaf(e4.x, A1.x, fmaf(e4.y, A1.y, fmaf(e4.z, A1.z, fmaf(e4.w, A1.w, eb1))));
            gg0 = fmaf(e4.x, G0.x, fmaf(e4.y, G0.y, fmaf(e4.z, G0.z, fmaf(e4.w, G0.w, gg0))));
            gg1 = fmaf(e4.x, G1.x, fmaf(e4.y, G1.y, fmaf(e4.z, G1.z, fmaf(e4.w, G1.w, gg1))));
        }
    }

    // 6) ehat -> LDS; per-head exp-sum and sigmoid-sum via wave shuffle
    {
        const float eh0 = a0 + eb0, eh1 = a1 + eb1;
        ehat_s[(2 * w) * PS + l]     = eh0;
        ehat_s[(2 * w + 1) * PS + l] = eh1;
        float p0 = __expf(eh0), p1 = __expf(eh1);
        float g0 = 1.f / (1.f + __expf(-gg0));
        float g1 = 1.f / (1.f + __expf(-gg1));
#pragma unroll
        for (int off = 32; off > 0; off >>= 1) {
            p0 += __shfl_xor(p0, off, 64);
            p1 += __shfl_xor(p1, off, 64);
            g0 += __shfl_xor(g0, off, 64);
            g1 += __shfl_xor(g1, off, 64);
        }
        if (l == 0) {
            ssb[2 * w] = p0; ssb[2 * w + 1] = p1;
            gsb[2 * w] = g0; gsb[2 * w + 1] = g1;
        }
    }
    __syncthreads();   // ehat/ssb/gsb ready; eb-phase done with e_tile

    // 7) e_out: thread owns chunk c -> row r, colgroup cc; ehat via LDS
    //    broadcast; nt full-line coalesced stores (16KB contiguous/block).
    {
        float4* eo = (float4*)(eout + ((size_t)bq * Nn + m0) * Dn);
#pragma unroll
        for (int j = 0; j < 4; ++j) {
            const int c = j * 256 + t, r = c >> 4, cc = c & 15;
            f32x4 o = {0.f, 0.f, 0.f, 0.f};
#pragma unroll
            for (int h = 0; h < Hn; ++h) {
                const float ehv = ehat_s[h * PS + r];
                const float4 w4 = *(const float4*)&oe_s[h][cc * 4];
                o.x = fmaf(ehv, w4.x, o.x);
                o.y = fmaf(ehv, w4.y, o.y);
                o.z = fmaf(ehv, w4.z, o.z);
                o.w = fmaf(ehv, w4.w, o.w);
            }
            __builtin_nontemporal_store(o, (f32x4*)eo + c);
        }
    }

    // 8) PV partials: wave w covers rows w*16..w*16+15; p = exp(ehat)
    {
        const int h = l >> 3;
        float acc = 0.f;
        const float* vrow = Vw + ((size_t)b * Nn + m0 + w * 16) * Dn;
#pragma unroll
        for (int i = 0; i < 16; ++i) {
            const float p = __expf(ehat_s[h * PS + w * 16 + i]);
            acc = fmaf(p, vrow[i * Dn + l], acc);
        }
        accb[w][l] = acc;
    }
    __syncthreads();

    // 9) fold 4 waves, emit 80-float partial
    if (w == 0) {
        const float O = accb[0][l] + accb[1][l] + accb[2][l] + accb[3][l];
        float* pb = part + (size_t)bid * PART;
        pb[l] = O;
        if (l < 8) { pb[64 + l] = ssb[l]; pb[72 + l] = gsb[l]; }
    }
}

// ---------------- Kernel 3: fold partials -> n_out ------------------------
__global__ __launch_bounds__(64) void reduce_kernel(
    const float* __restrict__ part, const float* __restrict__ WoG,
    float* __restrict__ nout)
{
    const int bq = blockIdx.x;
    const int l  = threadIdx.x;
    const int h  = l >> 3;
    const float* pb = part + (size_t)bq * NT * PART;
    float O = 0.f, S = 0.f, G = 0.f;
#pragma unroll
    for (int tl = 0; tl < NT; ++tl) {
        O += pb[tl * PART + l];
        S += pb[tl * PART + 64 + h];
        G += pb[tl * PART + 72 + h];
    }
    __shared__ float vo_s[Dn];
    vo_s[l] = (O / S) * log1pf(G);
    __syncthreads();
    float a = 0.f;
#pragma unroll
    for (int k = 0; k < Dn; ++k)
        a = fmaf(vo_s[k], WoG[k * Dn + l], a);
    nout[(size_t)bq * Dn + l] = a;
}

// ---------------- Host launcher -------------------------------------------
extern "C" void kernel_launch(void* const* d_in, const int* in_sizes, int n_in,
                              void* d_out, int out_size, void* d_ws, size_t ws_size,
                              hipStream_t stream)
{
    (void)in_sizes; (void)n_in; (void)out_size; (void)ws_size;
    const float* nin = (const float*)d_in[0];
    const float* e   = (const float*)d_in[1];
    const float* Wq  = (const float*)d_in[2];
    const float* Wk  = (const float*)d_in[3];
    const float* Wv  = (const float*)d_in[4];
    const float* Wo  = (const float*)d_in[5];
    const float* Wg  = (const float*)d_in[6];
    const float* We  = (const float*)d_in[7];
    const float* Oe  = (const float*)d_in[8];

    float* Qw   = (float*)d_ws;               // B*N*D floats
    float* Kw   = Qw + Bn * Nn * Dn;
    float* Vw   = Kw + Bn * Nn * Dn;
    float* part = Vw + Bn * Nn * Dn;          // B*N*NT*PART floats (5.2 MB)

    float* nout = (float*)d_out;              // B*N*D floats
    float* eout = nout + Bn * Nn * Dn;        // B*N*N*D floats

    qkv_kernel<<<Bn * Nn, 64, 0, stream>>>(nin, Wq, Wk, Wv, Qw, Kw, Vw);
    stream_kernel<<<Bn * Nn * NT, 256, 0, stream>>>(e, Qw, Kw, Vw, We, Wg, Oe,
                                                    eout, part);
    reduce_kernel<<<Bn * Nn, 64, 0, stream>>>(part, Wo, nout);
}